// Round 1
// baseline (340.286 us; speedup 1.0000x reference)
//
#include <hip/hip_runtime.h>

// DigitConvolutionalModel R7 — conv+fc1 compose into one 784->100 linear map
// (W1eff, bias folded as k=784 row). R6 staged x through LDS with 3 barriers;
// but each x element feeds exactly ONE wave's MFMA fragment (waves split N,
// not M) -> zero cross-wave reuse -> LDS staging was pure overhead and the
// phase barriers made memory issue bursty (~40% of HBM BW).
// R7: A fragments load DIRECTLY global->reg. BM=64, 4 waves, wave w owns 16
// rows and all 7 live n-tiles (t=7 dead tile dropped, -12.5% MFMA). Per kc a
// lane loads 8 consecutive floats of its row (2x dwordx4, 128B/row/kc, fully
// line-efficient), converts bf16 in-reg, MFMAs. No barriers in the main loop,
// LDS only for the tiny fc2 epilogue (29.7 KB) -> 4 blocks/CU, waves free-run
// -> continuous HBM issue. Bias row handled by guarded tail chunk (kc=24,
// q>=2 lanes get {1.0,0,...} constants instead of OOB loads).

typedef short  s16x8 __attribute__((ext_vector_type(8)));   // 8 bf16
typedef float  f32x4 __attribute__((ext_vector_type(4)));   // 16x16 acc

#define BM   64     // images per block (16 per wave)
#define HSTR 116    // hbuf row stride (floats): 4*116 mod 32 banks = 16 -> 2-way (free)
#define NT   8      // prep emits 8 n-tiles (t=7 all zero, unread)
#define NTL  7      // live n-tiles in main kernel
#define KC   25     // k-chunks of 32: k<784 data, k==784 bias, k<800 zero

__device__ __forceinline__ unsigned short f2bf_rtne(float f) {
    unsigned int u = __builtin_bit_cast(unsigned int, f);
    u = (u + 0x7fffu + ((u >> 16) & 1u)) >> 16;
    return (unsigned short)u;
}

// ---- prep: W1eff = conv (x) fc1 fold -> bf16 B-fragments + bias row --------
// bw[t][kc][lane][8]; lane(n=lane&15, q=lane>>4) holds
//   B[k = kc*32 + q*8 + j][n = t*16 + (lane&15)]
extern "C" __global__ void __launch_bounds__(256)
prep_w1eff(const float* __restrict__ W1, const float* __restrict__ cw9,
           const float* __restrict__ b1, unsigned short* __restrict__ bw)
{
    int id = blockIdx.x * 256 + threadIdx.x;
    if (id >= NT * KC * 64) return;
    int lane = id & 63;
    int kc   = (id >> 6) % KC;
    int t    = id / (KC * 64);
    int n    = t * 16 + (lane & 15);
    int k0   = kc * 32 + (lane >> 4) * 8;

    float cw[9];
#pragma unroll
    for (int i = 0; i < 9; ++i) cw[i] = cw9[i];

    unsigned short v[8];
#pragma unroll
    for (int j = 0; j < 8; ++j) {
        int k = k0 + j;
        float f = 0.f;
        if (n < 100) {
            if (k < 784) {
                int i = k / 28, jj = k % 28;
                for (int dr = 0; dr < 3; ++dr)
                    for (int dc = 0; dc < 3; ++dc) {
                        int a = i - dr, b = jj - dc;
                        if (a >= 0 && a < 26 && b >= 0 && b < 26)
                            f = fmaf(W1[(size_t)n * 676 + a * 26 + b],
                                     cw[dr * 3 + dc], f);
                    }
            } else if (k == 784) {
                f = b1[n];            // bias row; A supplies 1.0 at k=784
            }                         // 785..799: zero
        }
        v[j] = f2bf_rtne(f);
    }
    *(uint4*)(bw + (size_t)id * 8) = *(const uint4*)v;
}

// fp32x8 -> bf16x8 (round-half-up, same numerics as R6 phase 0b)
__device__ __forceinline__ s16x8 cvt8(float4 a, float4 b) {
    unsigned int ax = __builtin_bit_cast(unsigned int, a.x) + 0x8000u;
    unsigned int ay = __builtin_bit_cast(unsigned int, a.y) + 0x8000u;
    unsigned int az = __builtin_bit_cast(unsigned int, a.z) + 0x8000u;
    unsigned int aw = __builtin_bit_cast(unsigned int, a.w) + 0x8000u;
    unsigned int bx = __builtin_bit_cast(unsigned int, b.x) + 0x8000u;
    unsigned int by = __builtin_bit_cast(unsigned int, b.y) + 0x8000u;
    unsigned int bz = __builtin_bit_cast(unsigned int, b.z) + 0x8000u;
    unsigned int bw_ = __builtin_bit_cast(unsigned int, b.w) + 0x8000u;
    uint4 u;
    u.x = (ax >> 16) | (ay & 0xffff0000u);
    u.y = (az >> 16) | (aw & 0xffff0000u);
    u.z = (bx >> 16) | (by & 0xffff0000u);
    u.w = (bz >> 16) | (bw_ & 0xffff0000u);
    return __builtin_bit_cast(s16x8, u);
}

// ---------------------------- main kernel ----------------------------------
extern "C" __global__ void __launch_bounds__(256, 4)
digit_gemm(const float* __restrict__ x,
           const unsigned short* __restrict__ bw,
           const float* __restrict__ W2,
           const float* __restrict__ b2,
           float* __restrict__ out)
{
    __shared__ __align__(16) float hbuf[BM * HSTR];   // 29,696 B -> 4 blocks/CU

    const int tid  = threadIdx.x;
    const int lane = tid & 63;
    const int wv   = tid >> 6;       // 0..3: wave owns rows wv*16..wv*16+15
    const int q    = lane >> 4;      // k-quarter within 32-chunk
    const int mn   = lane & 15;      // m row (A) / n col (B) within tile
    const int m0   = blockIdx.x * BM;

    // lane's image row; A frag: lane(q,mn) holds A[m=mn][k = kc*32 + q*8 + j]
    const float* arow = x + (size_t)(m0 + wv * 16 + mn) * 784;
    const uint4* bwv  = (const uint4*)bw;

    f32x4 acc[NTL];
#pragma unroll
    for (int t = 0; t < NTL; ++t) {
        acc[t][0] = 0.f; acc[t][1] = 0.f; acc[t][2] = 0.f; acc[t][3] = 0.f;
    }

    // guarded A-chunk load: off = kc*32 + q*8 valid iff < 784 (else dummy
    // in-bounds read, value replaced by bias constants in the kc==24 fixup)
    float4 c0, c1;
    {
        const float* p = arow + q * 8;              // kc=0 always valid
        c0 = *(const float4*)p; c1 = *(const float4*)(p + 4);
    }

    for (int kc = 0; kc < KC; ++kc) {
        // prefetch next chunk's raw A (clamped; in-bounds dummy for tail lanes)
        int kn  = (kc + 1 < KC) ? kc + 1 : KC - 1;
        int off = kn * 32 + q * 8;
        const float* p = arow + (off < 784 ? off : 0);
        float4 n0 = *(const float4*)p;
        float4 n1 = *(const float4*)(p + 4);

        // B fragments for this chunk (204.8 KB total, L1/L2-hot, shared by
        // all waves/blocks)
        uint4 bvv[NTL];
#pragma unroll
        for (int t = 0; t < NTL; ++t)
            bvv[t] = bwv[(size_t)(t * KC + kc) * 64 + lane];

        s16x8 av = cvt8(c0, c1);
        if (kc == KC - 1) {
            // k = 768 + q*8 + j: q>=2 lanes are past the 784 data columns.
            // q==2,j==0 is the bias row (A=1.0); everything else zero.
            if (q >= 2) {
                uint4 z; z.x = (q == 2) ? 0x3F80u : 0u; z.y = 0u; z.z = 0u; z.w = 0u;
                av = __builtin_bit_cast(s16x8, z);
            }
        }

#pragma unroll
        for (int t = 0; t < NTL; ++t)
            acc[t] = __builtin_amdgcn_mfma_f32_16x16x32_bf16(
                av, __builtin_bit_cast(s16x8, bvv[t]), acc[t], 0, 0, 0);

        c0 = n0; c1 = n1;
    }

    // -------- epilogue: ReLU -> hbuf; C/D row(image) = q*4 + r, col = mn ----
#pragma unroll
    for (int t = 0; t < NTL; ++t)
#pragma unroll
        for (int r = 0; r < 4; ++r) {
            float v = acc[t][r];
            v = v > 0.f ? v : 0.f;
            hbuf[(wv * 16 + q * 4 + r) * HSTR + t * 16 + mn] = v;
        }
    __syncthreads();

    // -------- fc2 (fp32 VALU) + store --------------------------------------
    for (int p = tid; p < BM * 10; p += 256) {
        int mi = p / 10, o = p - mi * 10;
        const float4* hv = (const float4*)(hbuf + mi * HSTR);
        const float4* w2 = (const float4*)(W2 + (size_t)o * 100);
        float s = b2[o];
#pragma unroll
        for (int g = 0; g < 25; ++g) {
            float4 h4 = hv[g], w4 = w2[g];
            s += h4.x * w4.x + h4.y * w4.y + h4.z * w4.z + h4.w * w4.w;
        }
        out[(size_t)(m0 + mi) * 10 + o] = s;
    }
}

extern "C" void kernel_launch(void* const* d_in, const int* in_sizes, int n_in,
                              void* d_out, int out_size, void* d_ws, size_t ws_size,
                              hipStream_t stream) {
    const float* x  = (const float*)d_in[0];
    const float* cw = (const float*)d_in[1];
    const float* W1 = (const float*)d_in[2];
    const float* b1 = (const float*)d_in[3];
    const float* W2 = (const float*)d_in[4];
    const float* b2 = (const float*)d_in[5];
    float* out = (float*)d_out;
    unsigned short* bw = (unsigned short*)d_ws;    // NT*KC*64*8*2 = 204,800 B

    const int B = in_sizes[0] / 784;               // 65536

    hipLaunchKernelGGL(prep_w1eff, dim3((NT * KC * 64 + 255) / 256), dim3(256),
                       0, stream, W1, cw, b1, bw);
    hipLaunchKernelGGL(digit_gemm, dim3(B / BM), dim3(256), 0, stream,
                       x, bw, W2, b2, out);
}

// Round 2
// 321.667 us; speedup vs baseline: 1.0579x; 1.0579x over previous
//
#include <hip/hip_runtime.h>

// DigitConvolutionalModel R8 — conv+fc1 compose into one 784->100 linear map
// (W1eff, bias folded as k=784 row): out = relu(x@W1eff^T) @ W2^T + b2.
//
// R7 post-mortem: loading A fragments straight from global was a 16-row
// gather (32 discontiguous 64B lines per dwordx4) -> ~9M VMEM transactions
// through the TA; all pipes idle (MfmaUtil 3.5%, HBM 14%), 127us. The MFMA
// fragment layout requires a 16-row transpose; LDS staging IS that transpose
// with coalesced traffic. R8 reverts to the R6 skeleton (burst-load 8-deep
// coalesced -> bf16 LDS -> MFMA) and fixes its two measured costs:
//   (a) B-fragment loads were prefetched only 1-deep ->每-iter L2 stall.
//       Now: 3-deep prefetch ring + fully unrolled K-loop (VGPR headroom at
//       3 waves/EU) so ds_read/global_load/MFMA pipeline.
//   (b) wave 3's second n-tile (t=7, n=112..127) is all-zero and never read
//       by fc2 -> dropped (saves 12.5% of the B L2 transactions, the largest
//       transaction population: 179KB x 2048 blocks re-read through L2).
// BM=32 images/block, 256 thr, LDS 51.7 KB -> 3 blocks/CU; phases of the 3
// resident blocks stagger so the load phase keeps HBM issue continuous.

typedef short  s16x8 __attribute__((ext_vector_type(8)));   // 8 bf16
typedef float  f32x4 __attribute__((ext_vector_type(4)));   // 16x16 acc

#define BM   32     // images per block
#define XP   808    // xbuf row stride (bf16): 1616 B -> 16B-aligned, ~2-way banks
#define HSTR 132    // hbuf row stride (floats)
#define NT   8      // prep emits 8 n-tiles (t=7 all zero, unread)
#define KC   25     // k-chunks of 32: k<784 data, k==784 bias, k<800 zero

__device__ __forceinline__ unsigned short f2bf_rtne(float f) {
    unsigned int u = __builtin_bit_cast(unsigned int, f);
    u = (u + 0x7fffu + ((u >> 16) & 1u)) >> 16;
    return (unsigned short)u;
}

// ---- prep: W1eff = conv (x) fc1 fold -> bf16 B-fragments + bias row --------
// bw[t][kc][lane][8]; lane(n=lane&15, q=lane>>4) holds
//   B[k = kc*32 + q*8 + j][n = t*16 + (lane&15)]
extern "C" __global__ void __launch_bounds__(256)
prep_w1eff(const float* __restrict__ W1, const float* __restrict__ cw9,
           const float* __restrict__ b1, unsigned short* __restrict__ bw)
{
    int id = blockIdx.x * 256 + threadIdx.x;
    if (id >= NT * KC * 64) return;
    int lane = id & 63;
    int kc   = (id >> 6) % KC;
    int t    = id / (KC * 64);
    int n    = t * 16 + (lane & 15);
    int k0   = kc * 32 + (lane >> 4) * 8;

    float cw[9];
#pragma unroll
    for (int i = 0; i < 9; ++i) cw[i] = cw9[i];

    unsigned short v[8];
#pragma unroll
    for (int j = 0; j < 8; ++j) {
        int k = k0 + j;
        float f = 0.f;
        if (n < 100) {
            if (k < 784) {
                int i = k / 28, jj = k % 28;
                for (int dr = 0; dr < 3; ++dr)
                    for (int dc = 0; dc < 3; ++dc) {
                        int a = i - dr, b = jj - dc;
                        if (a >= 0 && a < 26 && b >= 0 && b < 26)
                            f = fmaf(W1[(size_t)n * 676 + a * 26 + b],
                                     cw[dr * 3 + dc], f);
                    }
            } else if (k == 784) {
                f = b1[n];            // bias row; A supplies 1.0 at k=784
            }                         // 785..799: zero
        }
        v[j] = f2bf_rtne(f);
    }
    *(uint4*)(bw + (size_t)id * 8) = *(const uint4*)v;
}

// ---- K-loop body: 2 m-tiles x NTILES n-tiles, 3-deep B prefetch ------------
template<int NTILES>
__device__ __forceinline__ void gemm_loop(
    const unsigned short* arow0, const unsigned short* arow1,
    const uint4* __restrict__ bwv, int t0, int t1, int lane,
    f32x4& acc00, f32x4& acc01, f32x4& acc10, f32x4& acc11)
{
    uint4 b0v[3], b1v[3];
#pragma unroll
    for (int i = 0; i < 3; ++i) {
        b0v[i] = bwv[(t0 * KC + i) * 64 + lane];
        if (NTILES == 2) b1v[i] = bwv[(t1 * KC + i) * 64 + lane];
    }
    uint4 a0 = *(const uint4*)(arow0);
    uint4 a1 = *(const uint4*)(arow1);
#pragma unroll
    for (int kc = 0; kc < KC; ++kc) {
        uint4 cb0 = b0v[kc % 3];
        uint4 cb1 = (NTILES == 2) ? b1v[kc % 3] : cb0;
        if (kc + 3 < KC) {                       // refill prefetch slot
            b0v[kc % 3] = bwv[(t0 * KC + kc + 3) * 64 + lane];
            if (NTILES == 2) b1v[kc % 3] = bwv[(t1 * KC + kc + 3) * 64 + lane];
        }
        uint4 na0 = a0, na1 = a1;
        if (kc + 1 < KC) {                       // 1-deep LDS prefetch
            na0 = *(const uint4*)(arow0 + (kc + 1) * 32);
            na1 = *(const uint4*)(arow1 + (kc + 1) * 32);
        }
        s16x8 av0 = __builtin_bit_cast(s16x8, a0);
        s16x8 av1 = __builtin_bit_cast(s16x8, a1);
        acc00 = __builtin_amdgcn_mfma_f32_16x16x32_bf16(
            av0, __builtin_bit_cast(s16x8, cb0), acc00, 0, 0, 0);
        acc10 = __builtin_amdgcn_mfma_f32_16x16x32_bf16(
            av1, __builtin_bit_cast(s16x8, cb0), acc10, 0, 0, 0);
        if (NTILES == 2) {
            acc01 = __builtin_amdgcn_mfma_f32_16x16x32_bf16(
                av0, __builtin_bit_cast(s16x8, cb1), acc01, 0, 0, 0);
            acc11 = __builtin_amdgcn_mfma_f32_16x16x32_bf16(
                av1, __builtin_bit_cast(s16x8, cb1), acc11, 0, 0, 0);
        }
        a0 = na0; a1 = na1;
    }
}

// ---------------------------- main kernel ----------------------------------
extern "C" __global__ void __launch_bounds__(256, 3)
digit_gemm(const float* __restrict__ x,
           const unsigned short* __restrict__ bw,
           const float* __restrict__ W2,
           const float* __restrict__ b2,
           float* __restrict__ out)
{
    __shared__ __align__(16) unsigned char smem[BM * XP * 2];  // 51712 B
    unsigned short* xbuf = (unsigned short*)smem;   // [32][808] bf16 (K-major)
    float*          hbuf = (float*)smem;            // epilogue alias

    const int tid  = threadIdx.x;
    const int lane = tid & 63;
    const int wv   = tid >> 6;       // 0..3
    const int q    = lane >> 4;      // k-quarter
    const int mn   = lane & 15;      // m row / n col within tile
    const int m0   = blockIdx.x * BM;

    // -------- Phase 0a: K-pad [784,800): bias-1.0 at 784, zeros after -------
    {   // 32 rows x 8 uints = 256 tasks, exactly one per thread
        int mi = tid >> 3, u = tid & 7;
        *(unsigned int*)(xbuf + mi * XP + 784 + u * 2) = (u == 0) ? 0x3F80u : 0u;
    }

    // -------- Phase 0b: burst-load x (8 loads in flight), bf16 -> xbuf ------
    // 32*784 floats = 6272 float4; thread handles g = tid + 256*i, bursts of 8
    const float4* xg = (const float4*)(x + (size_t)m0 * 784);
    for (int rr = 0; rr < 3; ++rr) {
        float4 v[8];
#pragma unroll
        for (int i = 0; i < 8; ++i)
            v[i] = xg[tid + 256 * (rr * 8 + i)];       // 8 independent loads
#pragma unroll
        for (int i = 0; i < 8; ++i) {
            int g  = tid + 256 * (rr * 8 + i);
            int mi = g / 196, c4 = g - mi * 196;       // 196 float4 per image
            unsigned int ax = __builtin_bit_cast(unsigned int, v[i].x) + 0x8000u;
            unsigned int ay = __builtin_bit_cast(unsigned int, v[i].y) + 0x8000u;
            unsigned int az = __builtin_bit_cast(unsigned int, v[i].z) + 0x8000u;
            unsigned int aw = __builtin_bit_cast(unsigned int, v[i].w) + 0x8000u;
            uint2 w;
            w.x = (ax >> 16) | (ay & 0xffff0000u);
            w.y = (az >> 16) | (aw & 0xffff0000u);
            *(uint2*)(xbuf + mi * XP + c4 * 4) = w;    // 8B-aligned
        }
    }
    if (tid < 128) {                                    // tail: g = 6144+tid
        int g  = 6144 + tid;
        float4 vv = xg[g];
        int mi = g / 196, c4 = g - mi * 196;
        unsigned int ax = __builtin_bit_cast(unsigned int, vv.x) + 0x8000u;
        unsigned int ay = __builtin_bit_cast(unsigned int, vv.y) + 0x8000u;
        unsigned int az = __builtin_bit_cast(unsigned int, vv.z) + 0x8000u;
        unsigned int aw = __builtin_bit_cast(unsigned int, vv.w) + 0x8000u;
        uint2 w;
        w.x = (ax >> 16) | (ay & 0xffff0000u);
        w.y = (az >> 16) | (aw & 0xffff0000u);
        *(uint2*)(xbuf + mi * XP + c4 * 4) = w;
    }
    __syncthreads();

    // -------- Phase 1: MFMA 16x16x32, 2 m-tiles x {2,1} n-tiles per wave ----
    // A: lane holds A[m=mn][k=q*8+j]; B: lane holds B[k=q*8+j][n=mn]
    f32x4 acc00, acc01, acc10, acc11;
#pragma unroll
    for (int i = 0; i < 4; ++i) { acc00[i]=0.f; acc01[i]=0.f; acc10[i]=0.f; acc11[i]=0.f; }

    const unsigned short* arow0 = xbuf + mn * XP + q * 8;          // images 0-15
    const unsigned short* arow1 = xbuf + (16 + mn) * XP + q * 8;   // images 16-31
    const uint4* bwv = (const uint4*)bw;
    const int t0 = wv, t1 = wv + 4;

    if (wv < 3)   // t1 in {4,5,6} live
        gemm_loop<2>(arow0, arow1, bwv, t0, t1, lane, acc00, acc01, acc10, acc11);
    else          // wave 3: t1==7 is the all-zero dead tile -> skip it
        gemm_loop<1>(arow0, arow1, bwv, t0, t1, lane, acc00, acc01, acc10, acc11);
    __syncthreads();          // xbuf reads drained; smem reusable as hbuf

    // -------- Phase 2a: ReLU -> hbuf; C/D row(image) = q*4 + r, col = mn ----
#pragma unroll
    for (int r = 0; r < 4; ++r) {
        int row = q * 4 + r;
        float v;
        v = acc00[r]; v = v > 0.f ? v : 0.f; hbuf[ row       * HSTR + t0 * 16 + mn] = v;
        v = acc10[r]; v = v > 0.f ? v : 0.f; hbuf[(row + 16) * HSTR + t0 * 16 + mn] = v;
        if (wv < 3) {
            v = acc01[r]; v = v > 0.f ? v : 0.f; hbuf[ row       * HSTR + t1 * 16 + mn] = v;
            v = acc11[r]; v = v > 0.f ? v : 0.f; hbuf[(row + 16) * HSTR + t1 * 16 + mn] = v;
        }
    }
    __syncthreads();

    // -------- Phase 2b: fc2 (fp32 VALU) + store -----------------------------
    for (int p = tid; p < BM * 10; p += 256) {
        int mi = p / 10, o = p - mi * 10;
        const float4* hv = (const float4*)(hbuf + mi * HSTR);
        const float4* w2 = (const float4*)(W2 + (size_t)o * 100);
        float s = b2[o];
#pragma unroll
        for (int g = 0; g < 25; ++g) {
            float4 h4 = hv[g], w4 = w2[g];
            s += h4.x*w4.x + h4.y*w4.y + h4.z*w4.z + h4.w*w4.w;
        }
        out[(size_t)(m0 + mi) * 10 + o] = s;
    }
}

extern "C" void kernel_launch(void* const* d_in, const int* in_sizes, int n_in,
                              void* d_out, int out_size, void* d_ws, size_t ws_size,
                              hipStream_t stream) {
    const float* x  = (const float*)d_in[0];
    const float* cw = (const float*)d_in[1];
    const float* W1 = (const float*)d_in[2];
    const float* b1 = (const float*)d_in[3];
    const float* W2 = (const float*)d_in[4];
    const float* b2 = (const float*)d_in[5];
    float* out = (float*)d_out;
    unsigned short* bw = (unsigned short*)d_ws;    // NT*KC*64*8*2 = 204,800 B

    const int B = in_sizes[0] / 784;               // 65536

    hipLaunchKernelGGL(prep_w1eff, dim3((NT * KC * 64 + 255) / 256), dim3(256),
                       0, stream, W1, cw, b1, bw);
    hipLaunchKernelGGL(digit_gemm, dim3(B / BM), dim3(256), 0, stream,
                       x, bw, W2, b2, out);
}

// Round 3
// 317.676 us; speedup vs baseline: 1.0712x; 1.0126x over previous
//
#include <hip/hip_runtime.h>

// DigitConvolutionalModel R9 — persistent double-buffered streaming GEMM.
// conv+fc1 compose into W1eff (bias as k=784 row): out = relu(x@W1eff^T)@W2^T+b2.
//
// R8 post-mortem: phase-serial blocks (load->barrier->compute->epilogue) with
// 3 aligned blocks/CU gave ~30% HBM duty (107us vs 32.6us floor for 205.5MB).
// R9: 256 persistent blocks (1/CU), 8 tiles each, double-buffered xbuf.
//   - steady loop's ONLY global loads are the next tile's A burst (25 dwordx4
//     per thread = 100KB/block in flight through the whole compute phase)
//   - B fragments in REGISTERS (loaded once from L2; 200 VGPR/lane; at
//     1 wave/SIMD the VGPR budget to ~450 is free), W2 in LDS -> no mid-loop
//     VMEM consumption that would in-order-drain the A queue
//   - raw s_barrier + explicit lgkmcnt(0) (not __syncthreads) so A loads
//     stay in flight across barriers
// LDS: 2*51712 (xbuf) + 4000 (W2) + 16896 (hbuf) = 124,320 B, 1 block/CU.

typedef short  s16x8 __attribute__((ext_vector_type(8)));   // 8 bf16
typedef float  f32x4 __attribute__((ext_vector_type(4)));   // 16x16 acc

#define BM   32     // images per tile
#define XP   808    // xbuf row stride (bf16): 1616 B
#define HSTR 132    // hbuf row stride (floats)
#define NT   8      // prep emits 8 n-tiles (t=7 all zero)
#define KC   25     // k-chunks of 32: k<784 data, k==784 bias, k<800 zero
#define GRID 256    // persistent blocks, 1 per CU

__device__ __forceinline__ unsigned short f2bf_rtne(float f) {
    unsigned int u = __builtin_bit_cast(unsigned int, f);
    u = (u + 0x7fffu + ((u >> 16) & 1u)) >> 16;
    return (unsigned short)u;
}

// ---- prep: W1eff = conv (x) fc1 fold -> bf16 B-fragments + bias row --------
// bw[t][kc][lane][8]; lane(n=lane&15, q=lane>>4) holds
//   B[k = kc*32 + q*8 + j][n = t*16 + (lane&15)]
extern "C" __global__ void __launch_bounds__(256)
prep_w1eff(const float* __restrict__ W1, const float* __restrict__ cw9,
           const float* __restrict__ b1, unsigned short* __restrict__ bw)
{
    int id = blockIdx.x * 256 + threadIdx.x;
    if (id >= NT * KC * 64) return;
    int lane = id & 63;
    int kc   = (id >> 6) % KC;
    int t    = id / (KC * 64);
    int n    = t * 16 + (lane & 15);
    int k0   = kc * 32 + (lane >> 4) * 8;

    float cw[9];
#pragma unroll
    for (int i = 0; i < 9; ++i) cw[i] = cw9[i];

    unsigned short v[8];
#pragma unroll
    for (int j = 0; j < 8; ++j) {
        int k = k0 + j;
        float f = 0.f;
        if (n < 100) {
            if (k < 784) {
                int i = k / 28, jj = k % 28;
                for (int dr = 0; dr < 3; ++dr)
                    for (int dc = 0; dc < 3; ++dc) {
                        int a = i - dr, b = jj - dc;
                        if (a >= 0 && a < 26 && b >= 0 && b < 26)
                            f = fmaf(W1[(size_t)n * 676 + a * 26 + b],
                                     cw[dr * 3 + dc], f);
                    }
            } else if (k == 784) {
                f = b1[n];            // bias row; A supplies 1.0 at k=784
            }                         // 785..799: zero
        }
        v[j] = f2bf_rtne(f);
    }
    *(uint4*)(bw + (size_t)id * 8) = *(const uint4*)v;
}

#define MFMA(a, b, c) __builtin_amdgcn_mfma_f32_16x16x32_bf16(a, b, c, 0, 0, 0)

template<int NTILES>
__device__ __forceinline__ void compute_tile(
    const unsigned short* arow0, const unsigned short* arow1,
    const uint4 (&br0)[KC], const uint4 (&br1)[KC],
    f32x4& acc00, f32x4& acc01, f32x4& acc10, f32x4& acc11)
{
#pragma unroll
    for (int kc = 0; kc < KC; ++kc) {
        uint4 a0 = *(const uint4*)(arow0 + kc * 32);   // ds_read_b128
        uint4 a1 = *(const uint4*)(arow1 + kc * 32);
        s16x8 av0 = __builtin_bit_cast(s16x8, a0);
        s16x8 av1 = __builtin_bit_cast(s16x8, a1);
        s16x8 bv0 = __builtin_bit_cast(s16x8, br0[kc]);
        acc00 = MFMA(av0, bv0, acc00);
        acc10 = MFMA(av1, bv0, acc10);
        if (NTILES == 2) {
            s16x8 bv1 = __builtin_bit_cast(s16x8, br1[kc]);
            acc01 = MFMA(av0, bv1, acc01);
            acc11 = MFMA(av1, bv1, acc11);
        }
    }
}

// lgkmcnt-only barrier: LDS writes visible, but global loads STAY in flight
__device__ __forceinline__ void bar_lds() {
    asm volatile("s_waitcnt lgkmcnt(0)" ::: "memory");
    __builtin_amdgcn_s_barrier();
}

// pack float4 pair -> 8 bf16 (round-half-up) and write 8B to LDS
__device__ __forceinline__ void cvt_store(unsigned short* dst, float4 f) {
    unsigned int ax = __builtin_bit_cast(unsigned int, f.x) + 0x8000u;
    unsigned int ay = __builtin_bit_cast(unsigned int, f.y) + 0x8000u;
    unsigned int az = __builtin_bit_cast(unsigned int, f.z) + 0x8000u;
    unsigned int aw = __builtin_bit_cast(unsigned int, f.w) + 0x8000u;
    uint2 w;
    w.x = (ax >> 16) | (ay & 0xffff0000u);
    w.y = (az >> 16) | (aw & 0xffff0000u);
    *(uint2*)dst = w;
}

// ---------------------------- main kernel ----------------------------------
extern "C" __global__ void __launch_bounds__(256, 1)
digit_gemm(const float* __restrict__ x,
           const unsigned short* __restrict__ bw,
           const float* __restrict__ W2,
           const float* __restrict__ b2,
           float* __restrict__ out,
           int ntiles)
{
    __shared__ __align__(16) unsigned short xbuf[2][BM * XP];  // 103,424 B
    __shared__ __align__(16) float w2buf[10 * 100];            //   4,000 B
    __shared__ __align__(16) float hbuf[BM * HSTR];            //  16,896 B

    const int tid  = threadIdx.x;
    const int lane = tid & 63;
    const int wv   = tid >> 6;       // 0..3
    const int q    = lane >> 4;      // k-quarter
    const int mn   = lane & 15;      // m row / n col within tile
    const int tile0 = blockIdx.x * ntiles;

    // -------- prologue ------------------------------------------------------
    // B fragments -> registers (once; L2/L3-hot, coalesced 1KB/wave per chunk)
    const uint4* bwv = (const uint4*)bw;
    const int t0 = wv, t1 = wv + 4;            // t1==7 (wave 3) is zero tile
    uint4 br0[KC], br1[KC];
#pragma unroll
    for (int kc = 0; kc < KC; ++kc) {
        br0[kc] = bwv[(t0 * KC + kc) * 64 + lane];
        br1[kc] = bwv[(t1 * KC + kc) * 64 + lane];
    }

    // W2 -> LDS (once); b2 -> per-thread regs for the fc2 slots
#pragma unroll
    for (int i = 0; i < 4; ++i) {
        int j = tid + 256 * i;
        if (j < 1000) w2buf[j] = W2[j];
    }
    const int p0 = tid,      mi0 = p0 / 10, o0 = p0 - mi0 * 10;
    const int p1 = tid + 256;
    const bool has1 = (p1 < BM * 10);
    const int mi1 = p1 / 10, o1 = p1 - mi1 * 10;
    const float bb0 = b2[o0];
    const float bb1 = has1 ? b2[o1] : 0.f;

    // K-pad [784,800) for BOTH buffers: bias-1.0 at 784, zeros after (static)
    {
        int mi = tid >> 3, u = tid & 7;
        unsigned int pv = (u == 0) ? 0x3F80u : 0u;
        *(unsigned int*)(&xbuf[0][mi * XP + 784 + u * 2]) = pv;
        *(unsigned int*)(&xbuf[1][mi * XP + 784 + u * 2]) = pv;
    }

    // first tile: load + convert + stage into buf 0
    {
        const float4* xg = (const float4*)(x + (size_t)tile0 * BM * 784);
        float4 v[25];
#pragma unroll
        for (int i = 0; i < 24; ++i) v[i] = xg[tid + 256 * i];
        if (tid < 128) v[24] = xg[6144 + tid];
#pragma unroll
        for (int i = 0; i < 25; ++i) {
            if (i < 24 || tid < 128) {
                int g = tid + 256 * i;
                int mi = g / 196, c4 = g - mi * 196;   // 196 float4 per image
                cvt_store(&xbuf[0][mi * XP + c4 * 4], v[i]);
            }
        }
    }
    bar_lds();

    // -------- persistent tile loop ------------------------------------------
    for (int t = 0; t < ntiles; ++t) {
        const int cur = t & 1;
        const int m0  = (tile0 + t) * BM;

        // issue next tile's A burst (the ONLY steady-state global loads);
        // 25 dwordx4/thread = 100KB/block in flight under the whole compute
        float4 v[25];
        const bool more = (t + 1 < ntiles);
        if (more) {
            const float4* xg = (const float4*)(x + (size_t)(tile0 + t + 1) * BM * 784);
#pragma unroll
            for (int i = 0; i < 24; ++i) v[i] = xg[tid + 256 * i];
            if (tid < 128) v[24] = xg[6144 + tid];
        }

        // ---- MFMA from LDS, B from registers (no VMEM here) ----------------
        f32x4 acc00, acc01, acc10, acc11;
#pragma unroll
        for (int i = 0; i < 4; ++i) { acc00[i]=0.f; acc01[i]=0.f; acc10[i]=0.f; acc11[i]=0.f; }
        const unsigned short* arow0 = &xbuf[cur][mn * XP + q * 8];        // img 0-15
        const unsigned short* arow1 = &xbuf[cur][(16 + mn) * XP + q * 8]; // img 16-31
        if (wv < 3)
            compute_tile<2>(arow0, arow1, br0, br1, acc00, acc01, acc10, acc11);
        else
            compute_tile<1>(arow0, arow1, br0, br1, acc00, acc01, acc10, acc11);

        // ---- ReLU -> hbuf; C/D row(image) = q*4 + r, col(neuron) = mn ------
#pragma unroll
        for (int r = 0; r < 4; ++r) {
            int row = q * 4 + r;
            float z;
            z = acc00[r]; z = z > 0.f ? z : 0.f; hbuf[ row       * HSTR + t0 * 16 + mn] = z;
            z = acc10[r]; z = z > 0.f ? z : 0.f; hbuf[(row + 16) * HSTR + t0 * 16 + mn] = z;
            if (wv < 3) {
                z = acc01[r]; z = z > 0.f ? z : 0.f; hbuf[ row       * HSTR + t1 * 16 + mn] = z;
                z = acc11[r]; z = z > 0.f ? z : 0.f; hbuf[(row + 16) * HSTR + t1 * 16 + mn] = z;
            }
        }
        bar_lds();                                  // (a) hbuf ready

        // ---- fc2 (fp32 VALU, W2 from LDS) + store --------------------------
        {
            const float4* hv = (const float4*)(hbuf + mi0 * HSTR);
            const float4* w2 = (const float4*)(w2buf + o0 * 100);
            float s = bb0;
#pragma unroll
            for (int g = 0; g < 25; ++g) {
                float4 h4 = hv[g], w4 = w2[g];
                s += h4.x*w4.x + h4.y*w4.y + h4.z*w4.z + h4.w*w4.w;
            }
            out[(size_t)(m0 + mi0) * 10 + o0] = s;
        }
        if (has1) {
            const float4* hv = (const float4*)(hbuf + mi1 * HSTR);
            const float4* w2 = (const float4*)(w2buf + o1 * 100);
            float s = bb1;
#pragma unroll
            for (int g = 0; g < 25; ++g) {
                float4 h4 = hv[g], w4 = w2[g];
                s += h4.x*w4.x + h4.y*w4.y + h4.z*w4.z + h4.w*w4.w;
            }
            out[(size_t)(m0 + mi1) * 10 + o1] = s;
        }

        // ---- drain A burst (vmcnt waits inserted per-use), stage buf^1 -----
        if (more) {
            unsigned short* xb = &xbuf[cur ^ 1][0];
#pragma unroll
            for (int i = 0; i < 25; ++i) {
                if (i < 24 || tid < 128) {
                    int g = tid + 256 * i;
                    int mi = g / 196, c4 = g - mi * 196;
                    cvt_store(xb + mi * XP + c4 * 4, v[i]);
                }
            }
        }
        bar_lds();                                  // (b) xbuf^1 ready, hbuf free
    }
}

extern "C" void kernel_launch(void* const* d_in, const int* in_sizes, int n_in,
                              void* d_out, int out_size, void* d_ws, size_t ws_size,
                              hipStream_t stream) {
    const float* x  = (const float*)d_in[0];
    const float* cw = (const float*)d_in[1];
    const float* W1 = (const float*)d_in[2];
    const float* b1 = (const float*)d_in[3];
    const float* W2 = (const float*)d_in[4];
    const float* b2 = (const float*)d_in[5];
    float* out = (float*)d_out;
    unsigned short* bw = (unsigned short*)d_ws;    // NT*KC*64*8*2 = 204,800 B

    const int B = in_sizes[0] / 784;               // 65536
    const int ntiles = (B / BM) / GRID;            // 2048 tiles / 256 blocks = 8

    hipLaunchKernelGGL(prep_w1eff, dim3((NT * KC * 64 + 255) / 256), dim3(256),
                       0, stream, W1, cw, b1, bw);
    hipLaunchKernelGGL(digit_gemm, dim3(GRID), dim3(256), 0, stream,
                       x, bw, W2, b2, out, ntiles);
}